// Round 1
// baseline (220.364 us; speedup 1.0000x reference)
//
#include <hip/hip_runtime.h>
#include <hip/hip_bf16.h>

// DiagWinAttention: nw=4096 windows, N=64 tokens, E=96 = 6 heads x 16
// One block per window, 384 threads = 6 waves, wave h owns head h.
// bf16 MFMA 16x16x16 (K=16 == CH, no padding) for QK^T, PV, and projection.

typedef short v4s __attribute__((ext_vector_type(4)));
typedef float v4f __attribute__((ext_vector_type(4)));

#define MFMA16(A, B, C) __builtin_amdgcn_mfma_f32_16x16x16bf16_1k(A, B, C, 0, 0, 0)

__device__ __forceinline__ ushort f2b(float x) {
  union { __hip_bfloat16 h; ushort u; } c; c.h = __float2bfloat16(x); return c.u;
}
__device__ __forceinline__ float b2f(ushort u) {
  union { ushort u; __hip_bfloat16 h; } c; c.u = u; return __bfloat162float(c.h);
}

// LDS strides (bf16 units), chosen for 8B alignment + conflict-free ds_read_b64:
// row stride 100 bf16 = 50 dwords -> bank step 18 mod 32, 16 distinct banks.
#define SQK 100   // Q,K,V rows
#define SMS 68    // mask rows (transposed-tiled: slot = (c&15)*4 + (c>>4))
#define SPP 20    // P transpose chunk rows (16 cols + pad)
#define SXX 100   // X / Xn rows

__global__ __launch_bounds__(384, 3)
void winattn_kernel(const float* __restrict__ gQ, const float* __restrict__ gK,
                    const float* __restrict__ gV, const float* __restrict__ gM,
                    const float* __restrict__ gBT, const float* __restrict__ gGa,
                    const float* __restrict__ gBe, const float* __restrict__ gW,
                    const float* __restrict__ gPb, float* __restrict__ gO)
{
  __shared__ ushort sQ[64 * SQK];       // 12800 B, q * 0.25 (scaled: used for QK and residual)
  __shared__ ushort sK[64 * SQK];       // 12800 B
  __shared__ ushort sV[64 * SQK];       // 12800 B
  __shared__ ushort sM[64 * SMS];       //  8704 B
  __shared__ float  sB[225 * 6];        //  5400 B  rel-pos bias table
  __shared__ float  sG[96];             //   384 B
  __shared__ float  sBe[96];            //   384 B
  __shared__ ushort sU[12800];          // 25600 B union: P chunks (7680) | X (6400) + Xn (6400)
  // total 78872 B -> 2 blocks/CU

  const int tid  = threadIdx.x;
  const int w    = blockIdx.x;
  const int wave = tid >> 6;            // head 0..5
  const int lane = tid & 63;
  const int l15  = lane & 15;
  const int g    = lane >> 4;           // 16-lane group 0..3

  const size_t base = (size_t)w * (64 * 96);
  const float4* q4 = (const float4*)(gQ + base);
  const float4* k4 = (const float4*)(gK + base);
  const float4* v4 = (const float4*)(gV + base);
  const float4* m4 = (const float4*)(gM + (size_t)w * (64 * 64));

  // ---------------- stage: QKV -> bf16 LDS (coalesced float4 reads) ----------------
  #pragma unroll
  for (int i = 0; i < 4; ++i) {
    const int idx = tid + i * 384;            // 1536 float4 per tensor
    const int r = idx / 24, c = (idx % 24) * 4;
    float4 a = q4[idx];
    ushort4 ua; ua.x = f2b(a.x * 0.25f); ua.y = f2b(a.y * 0.25f);
    ua.z = f2b(a.z * 0.25f); ua.w = f2b(a.w * 0.25f);
    *(ushort4*)&sQ[r * SQK + c] = ua;
    float4 b = k4[idx];
    ushort4 ub; ub.x = f2b(b.x); ub.y = f2b(b.y); ub.z = f2b(b.z); ub.w = f2b(b.w);
    *(ushort4*)&sK[r * SQK + c] = ub;
    float4 vv = v4[idx];
    ushort4 uv; uv.x = f2b(vv.x); uv.y = f2b(vv.y); uv.z = f2b(vv.z); uv.w = f2b(vv.w);
    *(ushort4*)&sV[r * SQK + c] = uv;
  }
  // mask: transposed-tiled so softmax reads one ushort4 (all 4 col-tiles) per row
  #pragma unroll
  for (int i = 0; i < 3; ++i) {
    const int idx = tid + i * 384;            // 1024 float4
    if (idx < 1024) {
      const int r = idx >> 4, c0 = (idx & 15) * 4;
      float4 a = m4[idx];
      float vals[4] = {a.x, a.y, a.z, a.w};
      #pragma unroll
      for (int e = 0; e < 4; ++e) {
        const int c = c0 + e;
        sM[r * SMS + (c & 15) * 4 + (c >> 4)] = f2b(vals[e]);
      }
    }
  }
  for (int i = tid; i < 1350; i += 384) sB[i] = gBT[i];
  if (tid < 96) { sG[tid] = gGa[tid]; sBe[tid] = gBe[tid]; }

  // ---------------- per-wave projection-W fragments (kept in regs) ----------------
  const int oc = l15 + 16 * wave;            // this wave's output column block
  v4s wf[6];
  #pragma unroll
  for (int kk = 0; kk < 6; ++kk) {
    float4 wv = *(const float4*)(gW + oc * 96 + kk * 16 + 4 * g);
    wf[kk] = (v4s){ (short)f2b(wv.x), (short)f2b(wv.y), (short)f2b(wv.z), (short)f2b(wv.w) };
  }
  const float pbias = gPb[oc];

  __syncthreads();

  // ---------------- QK^T: S = (q*scale) @ K^T, 4x4 tiles of 16x16, K=16 ----------------
  v4f acc[4][4];
  #pragma unroll
  for (int mt = 0; mt < 4; ++mt)
    #pragma unroll
    for (int nt = 0; nt < 4; ++nt)
      acc[mt][nt] = (v4f){0.f, 0.f, 0.f, 0.f};
  {
    const int co = 16 * wave + 4 * g;        // channel offset for this head / k-group
    v4s aq[4], bk[4];
    #pragma unroll
    for (int t = 0; t < 4; ++t) {
      aq[t] = *(const v4s*)&sQ[(l15 + 16 * t) * SQK + co];
      bk[t] = *(const v4s*)&sK[(l15 + 16 * t) * SQK + co];
    }
    #pragma unroll
    for (int mt = 0; mt < 4; ++mt)
      #pragma unroll
      for (int nt = 0; nt < 4; ++nt)
        acc[mt][nt] = MFMA16(aq[mt], bk[nt], acc[mt][nt]);
  }

  // ---------------- + rel-pos bias + mask, then row softmax ----------------
  // C-layout: element (row = 16*mt + 4*g + rg, col = 16*nt + l15)
  float rowm[4][4], rs_[4][4];
  #pragma unroll
  for (int mt = 0; mt < 4; ++mt) {
    #pragma unroll
    for (int rg = 0; rg < 4; ++rg) {
      const int r = 16 * mt + 4 * g + rg;
      const int yi = r >> 3, xi = r & 7;
      const ushort4 mrow = *(const ushort4*)&sM[r * SMS + l15 * 4];
      const ushort mv[4] = {mrow.x, mrow.y, mrow.z, mrow.w};
      float mx = -3.0e38f;
      #pragma unroll
      for (int nt = 0; nt < 4; ++nt) {
        const int c = 16 * nt + l15;
        const int bidx = (yi - (c >> 3) + 7) * 15 + (xi - (c & 7) + 7);
        float val = acc[mt][nt][rg] + sB[bidx * 6 + wave] + b2f(mv[nt]);
        acc[mt][nt][rg] = val;
        mx = fmaxf(mx, val);
      }
      rowm[mt][rg] = mx;
    }
  }
  #pragma unroll
  for (int msk = 1; msk <= 8; msk <<= 1)
    #pragma unroll
    for (int mt = 0; mt < 4; ++mt)
      #pragma unroll
      for (int rg = 0; rg < 4; ++rg)
        rowm[mt][rg] = fmaxf(rowm[mt][rg], __shfl_xor(rowm[mt][rg], msk, 64));

  #pragma unroll
  for (int mt = 0; mt < 4; ++mt)
    #pragma unroll
    for (int rg = 0; rg < 4; ++rg) {
      float s = 0.f;
      #pragma unroll
      for (int nt = 0; nt < 4; ++nt) {
        float e = __expf(acc[mt][nt][rg] - rowm[mt][rg]);
        acc[mt][nt][rg] = e;
        s += e;
      }
      rs_[mt][rg] = s;
    }
  #pragma unroll
  for (int msk = 1; msk <= 8; msk <<= 1)
    #pragma unroll
    for (int mt = 0; mt < 4; ++mt)
      #pragma unroll
      for (int rg = 0; rg < 4; ++rg)
        rs_[mt][rg] += __shfl_xor(rs_[mt][rg], msk, 64);
  #pragma unroll
  for (int mt = 0; mt < 4; ++mt)
    #pragma unroll
    for (int rg = 0; rg < 4; ++rg)
      rs_[mt][rg] = __builtin_amdgcn_rcpf(rs_[mt][rg]);   // defer division to O

  // ---------------- V fragments (column reads from LDS) ----------------
  v4s vf[4];
  {
    const int vc = 16 * wave + l15;
    #pragma unroll
    for (int kk = 0; kk < 4; ++kk) {
      const int kr = kk * 16 + 4 * g;
      vf[kk] = (v4s){ (short)sV[(kr + 0) * SQK + vc], (short)sV[(kr + 1) * SQK + vc],
                      (short)sV[(kr + 2) * SQK + vc], (short)sV[(kr + 3) * SQK + vc] };
    }
  }

  // ---------------- PV: O = P @ V via per-wave LDS transpose chunks ----------------
  v4f oa[4];
  #pragma unroll
  for (int mt = 0; mt < 4; ++mt) oa[mt] = (v4f){0.f, 0.f, 0.f, 0.f};
  ushort* pbuf = &sU[wave * (64 * SPP)];
  #pragma unroll
  for (int kk = 0; kk < 4; ++kk) {          // k-chunk = S column-tile kk
    #pragma unroll
    for (int mt = 0; mt < 4; ++mt)
      #pragma unroll
      for (int rg = 0; rg < 4; ++rg)
        pbuf[(16 * mt + 4 * g + rg) * SPP + l15] = f2b(acc[mt][kk][rg]);
    asm volatile("s_waitcnt lgkmcnt(0)" ::: "memory");   // wave-internal transpose visibility
    #pragma unroll
    for (int mt = 0; mt < 4; ++mt) {
      v4s pa = *(const v4s*)&pbuf[(l15 + 16 * mt) * SPP + 4 * g];
      oa[mt] = MFMA16(pa, vf[kk], oa[mt]);
    }
  }

  // normalize rows + residual (+q*scale)
  #pragma unroll
  for (int mt = 0; mt < 4; ++mt)
    #pragma unroll
    for (int rg = 0; rg < 4; ++rg) {
      const int r = 16 * mt + 4 * g + rg;
      oa[mt][rg] = oa[mt][rg] * rs_[mt][rg] + b2f(sQ[r * SQK + 16 * wave + l15]);
    }

  __syncthreads();                           // all waves done with P region

  // ---------------- X = concat heads (bf16) ----------------
  ushort* sX = sU;
  #pragma unroll
  for (int mt = 0; mt < 4; ++mt)
    #pragma unroll
    for (int rg = 0; rg < 4; ++rg)
      sX[(16 * mt + 4 * g + rg) * SXX + 16 * wave + l15] = f2b(oa[mt][rg]);

  __syncthreads();

  // ---------------- LayerNorm over 96 (lane -> row = lane; redundant per wave) ----------------
  float sum = 0.f, sq = 0.f;
  #pragma unroll
  for (int i = 0; i < 24; ++i) {
    ushort4 u = *(const ushort4*)&sX[lane * SXX + i * 4];
    float x0 = b2f(u.x), x1 = b2f(u.y), x2 = b2f(u.z), x3 = b2f(u.w);
    sum += x0 + x1 + x2 + x3;
    sq  += x0 * x0 + x1 * x1 + x2 * x2 + x3 * x3;
  }
  const float mu   = sum * (1.f / 96.f);
  const float var  = sq * (1.f / 96.f) - mu * mu;
  const float rsig = __builtin_amdgcn_rsqf(var + 1e-5f);
  ushort* sXn = &sU[6400];
  #pragma unroll
  for (int i = 0; i < 4; ++i) {
    const int c = 16 * wave + i * 4;
    ushort4 u = *(const ushort4*)&sX[lane * SXX + c];
    ushort4 o;
    o.x = f2b((b2f(u.x) - mu) * rsig * sG[c + 0] + sBe[c + 0]);
    o.y = f2b((b2f(u.y) - mu) * rsig * sG[c + 1] + sBe[c + 1]);
    o.z = f2b((b2f(u.z) - mu) * rsig * sG[c + 2] + sBe[c + 2]);
    o.w = f2b((b2f(u.w) - mu) * rsig * sG[c + 3] + sBe[c + 3]);
    *(ushort4*)&sXn[lane * SXX + c] = o;
  }

  __syncthreads();

  // ---------------- projection: Y = Xn @ W^T + b ----------------
  v4f ya[4];
  #pragma unroll
  for (int mt = 0; mt < 4; ++mt) ya[mt] = (v4f){0.f, 0.f, 0.f, 0.f};
  #pragma unroll
  for (int kk = 0; kk < 6; ++kk) {
    #pragma unroll
    for (int mt = 0; mt < 4; ++mt) {
      v4s xa = *(const v4s*)&sXn[(l15 + 16 * mt) * SXX + kk * 16 + 4 * g];
      ya[mt] = MFMA16(xa, wf[kk], ya[mt]);
    }
  }
  float* outp = gO + base;
  #pragma unroll
  for (int mt = 0; mt < 4; ++mt)
    #pragma unroll
    for (int rg = 0; rg < 4; ++rg)
      outp[(16 * mt + 4 * g + rg) * 96 + oc] = ya[mt][rg] + pbias;
}

extern "C" void kernel_launch(void* const* d_in, const int* in_sizes, int n_in,
                              void* d_out, int out_size, void* d_ws, size_t ws_size,
                              hipStream_t stream) {
  (void)in_sizes; (void)n_in; (void)out_size; (void)d_ws; (void)ws_size;
  winattn_kernel<<<dim3(4096), dim3(384), 0, stream>>>(
      (const float*)d_in[0], (const float*)d_in[1], (const float*)d_in[2],
      (const float*)d_in[3], (const float*)d_in[4], (const float*)d_in[5],
      (const float*)d_in[6], (const float*)d_in[7], (const float*)d_in[8],
      (float*)d_out);
}